// Round 4
// baseline (112.505 us; speedup 1.0000x reference)
//
#include <hip/hip_runtime.h>
#include <math.h>

// SemiConv2d tropical conv: out = max_{ic,kh,kw} min(x_pad, K). f16-packed.
// R4: explicit software pipeline (prefetch next-ic window regs) + HT=2 thread
// tile (4oc x 2h x 2w = 16 outputs/thread) + hp-fastest block order for XCD/L2
// locality. R3 evidence: VGPR=16 (no pipelining, latency-bound at ~20% issue),
// FETCH 38.8MB = 4x unique (each XCD streamed all of x through its 4MB L2).
//
// ws layout (u32 units): xh[n][ic][98][48] pairs (x[2j],x[2j+1]),
// xs[n][ic][98][49] shifted pairs (x[2j-1],x[2j]), k2[ocb][ic][4][9] duplicated
// f16 pairs. -inf baked into h rows 0/97 and w edges -> no edge handling.

#define HH 96
#define WW 96
#define CIN 32
#define OCN 32
#define XH_ROWS 98
#define XH_W 48
#define XS_W 49
#define XH_SLICE (XH_ROWS * XH_W)
#define XS_SLICE (XH_ROWS * XS_W)
#define XH_TOTAL (8 * 32 * XH_SLICE)
#define XS_TOTAL (8 * 32 * XS_SLICE)
#define K2_TOTAL (8 * 32 * 4 * 9)
#define WS_NEED ((size_t)(XH_TOTAL + XS_TOTAL + K2_TOTAL) * 4)

typedef _Float16 h2 __attribute__((ext_vector_type(2)));

__device__ __forceinline__ h2 hmin2(h2 a, h2 b) { return __builtin_elementwise_min(a, b); }
__device__ __forceinline__ h2 hmax2(h2 a, h2 b) { return __builtin_elementwise_max(a, b); }

__global__ __launch_bounds__(256) void setup_x(const float* __restrict__ x,
                                               h2* __restrict__ xh, h2* __restrict__ xs) {
    int idx = blockIdx.x * 256 + threadIdx.x;       // over 8*32*98*49 = 1,229,312
    int j  = idx % XS_W;
    int t  = idx / XS_W;
    int hp = t % XH_ROWS;
    int s  = t / XH_ROWS;                           // n*32+ic
    int h  = hp - 1;
    bool hv = (h >= 0) && (h < HH);
    const float* row = x + ((size_t)s * HH + (hv ? h : 0)) * WW;
    float xl = (hv && j > 0)  ? row[2 * j - 1] : -INFINITY;
    float xm = (hv && j < 48) ? row[2 * j]     : -INFINITY;
    float xr = (hv && j < 48) ? row[2 * j + 1] : -INFINITY;
    xs[idx] = h2{(_Float16)xl, (_Float16)xm};
    if (j < 48)
        xh[(t) * XH_W + j] = h2{(_Float16)xm, (_Float16)xr};
}

__global__ __launch_bounds__(256) void setup_k(const float* __restrict__ kk, h2* __restrict__ k2) {
    int idx = blockIdx.x * 256 + threadIdx.x;       // over 9216
    int tap  = idx % 9;
    int ocin = (idx / 9) % 4;
    int ic   = (idx / 36) % CIN;
    int ocb  = idx / (36 * CIN);
    float v = kk[(((ocb * 4 + ocin) * CIN) + ic) * 9 + tap];
    _Float16 hv = (_Float16)v;
    k2[idx] = h2{hv, hv};
}

__global__ __launch_bounds__(192) void semiconv_f16(const h2* __restrict__ xh,
                                                    const h2* __restrict__ xs,
                                                    const h2* __restrict__ k2,
                                                    float* __restrict__ out) {
    const int tid = threadIdx.x;
    const int jj = tid % 48;          // w-pair 0..47
    const int hr = tid / 48;          // 0..3
    const int b  = blockIdx.x;
    const int hp  = b % 12;           // hp FASTEST -> round-robin XCDs get
    const int t   = b / 12;           //   disjoint hp stripes, reused over ocb
    const int ocb = t & 7;
    const int n   = t >> 3;
    const int h0  = hp * 8 + hr * 2;  // output rows h0, h0+1

    // xh/xs row r here = x row (h0-1+r); window for outputs h0,h0+1 = rows 0..3
    const h2* xhp = xh + ((size_t)(n * CIN) * XH_ROWS + h0) * XH_W + jj;
    const h2* xsp = xs + ((size_t)(n * CIN) * XH_ROWS + h0) * XS_W + jj;
    const h2* kp  = k2 + (size_t)ocb * CIN * 36;

    const _Float16 NI = (_Float16)(-INFINITY);
    h2 acc[4][2];
#pragma unroll
    for (int oc = 0; oc < 4; ++oc) { acc[oc][0] = h2{NI, NI}; acc[oc][1] = h2{NI, NI}; }

    // prologue: load window for ic=0
    h2 cw[4][3];
#pragma unroll
    for (int r = 0; r < 4; ++r) {
        cw[r][0] = xsp[r * XS_W];
        cw[r][1] = xhp[r * XH_W];
        cw[r][2] = xsp[r * XS_W + 1];
    }

    for (int ic = 0; ic < CIN; ++ic) {
        // prefetch next ic's window (clamped at the last iter: harmless reload)
        const int step = (ic < CIN - 1) ? 1 : 0;
        const h2* nxh = xhp + step * XH_SLICE;
        const h2* nxs = xsp + step * XS_SLICE;
        h2 nw[4][3];
#pragma unroll
        for (int r = 0; r < 4; ++r) {
            nw[r][0] = nxs[r * XS_W];
            nw[r][1] = nxh[r * XH_W];
            nw[r][2] = nxs[r * XS_W + 1];
        }

        const h2* kq0 = kp + ic * 36;
#pragma unroll
        for (int oc = 0; oc < 4; ++oc) {
            const h2* kq = kq0 + oc * 9;           // wave-uniform -> s_load
#pragma unroll
            for (int r = 0; r < 3; ++r)
#pragma unroll
                for (int c = 0; c < 3; ++c) {
                    h2 kv = kq[r * 3 + c];
                    acc[oc][0] = hmax2(acc[oc][0], hmin2(cw[r][c],     kv));
                    acc[oc][1] = hmax2(acc[oc][1], hmin2(cw[r + 1][c], kv));
                }
        }

#pragma unroll
        for (int r = 0; r < 4; ++r) {
            cw[r][0] = nw[r][0]; cw[r][1] = nw[r][1]; cw[r][2] = nw[r][2];
        }
        xhp = nxh;
        xsp = nxs;
    }

#pragma unroll
    for (int oc = 0; oc < 4; ++oc)
#pragma unroll
        for (int o = 0; o < 2; ++o) {
            float2 v = make_float2((float)acc[oc][o].x, (float)acc[oc][o].y);
            *(float2*)(out + (((size_t)(n * OCN + ocb * 4 + oc)) * HH + h0 + o) * WW + 2 * jj) = v;
        }
}

// ---------- f32 fallback if ws is too small ----------
#define NEGINF (-INFINITY)
__global__ __launch_bounds__(192, 8) void semiconv2d_f32(
    const float* __restrict__ x, const float* __restrict__ kk, float* __restrict__ out)
{
    const int tid = threadIdx.x;
    const int w  = tid % WW;
    const int hr = tid / WW;
    const int b   = blockIdx.x;
    const int ocb = b & 7;
    const int hp  = (b >> 3) % 48;
    const int n   = (b >> 3) / 48;
    const int h   = hp * 2 + hr;
    const int oc0 = ocb * 4;
    float a0[4], a1[4], a2[4];
#pragma unroll
    for (int i = 0; i < 4; ++i) { a0[i] = NEGINF; a1[i] = NEGINF; a2[i] = NEGINF; }
    const bool vm = (h > 0), vp = (h < HH - 1);
    const int hm  = vm ? h - 1 : h;
    const int hpl = vp ? h + 1 : h;
    const int cm  = (w > 0) ? -1 : 0;
    const int cp  = (w < WW - 1) ? 1 : 0;
    const float* rm = x + ((size_t)(n * CIN) * HH + hm)  * WW + w;
    const float* r1 = x + ((size_t)(n * CIN) * HH + h)   * WW + w;
    const float* rp = x + ((size_t)(n * CIN) * HH + hpl) * WW + w;
#pragma unroll 2
    for (int ic = 0; ic < CIN; ++ic) {
        float r00 = vm ? rm[cm] : NEGINF, r01 = vm ? rm[0] : NEGINF, r02 = vm ? rm[cp] : NEGINF;
        float r10 = r1[cm], r11 = r1[0], r12 = r1[cp];
        float r20 = vp ? rp[cm] : NEGINF, r21 = vp ? rp[0] : NEGINF, r22 = vp ? rp[cp] : NEGINF;
#pragma unroll
        for (int oc = 0; oc < 4; ++oc) {
            const float* kq = kk + (size_t)(((oc0 + oc) * CIN + ic)) * 9;
            a0[oc] = fmaxf(fmaxf(a0[oc], fminf(r00, kq[0])), fmaxf(fminf(r10, kq[3]), fminf(r20, kq[6])));
            a1[oc] = fmaxf(fmaxf(a1[oc], fminf(r01, kq[1])), fmaxf(fminf(r11, kq[4]), fminf(r21, kq[7])));
            a2[oc] = fmaxf(fmaxf(a2[oc], fminf(r02, kq[2])), fmaxf(fminf(r12, kq[5]), fminf(r22, kq[8])));
        }
        rm += HH * WW; r1 += HH * WW; rp += HH * WW;
    }
#pragma unroll
    for (int oc = 0; oc < 4; ++oc) {
        float v0 = (w > 0)      ? a0[oc] : NEGINF;
        float v2 = (w < WW - 1) ? a2[oc] : NEGINF;
        out[(((size_t)(n * OCN + oc0 + oc)) * HH + h) * WW + w] = fmaxf(fmaxf(v0, a1[oc]), v2);
    }
}

extern "C" void kernel_launch(void* const* d_in, const int* in_sizes, int n_in,
                              void* d_out, int out_size, void* d_ws, size_t ws_size,
                              hipStream_t stream) {
    const float* x  = (const float*)d_in[0];
    const float* kk = (const float*)d_in[1];
    float* out      = (float*)d_out;
    if (ws_size >= WS_NEED) {
        h2* xh = (h2*)d_ws;
        h2* xs = xh + XH_TOTAL;
        h2* k2 = xs + XS_TOTAL;
        setup_x<<<dim3((8 * 32 * XH_ROWS * XS_W) / 256), dim3(256), 0, stream>>>(x, xh, xs);
        setup_k<<<dim3(K2_TOTAL / 256), dim3(256), 0, stream>>>(kk, k2);
        semiconv_f16<<<dim3(8 * 8 * 12), dim3(192), 0, stream>>>(xh, xs, k2, out);
    } else {
        semiconv2d_f32<<<dim3(8 * 48 * 8), dim3(192), 0, stream>>>(x, kk, out);
    }
}